// Round 1
// baseline (1239.002 us; speedup 1.0000x reference)
//
#include <hip/hip_runtime.h>
#include <math.h>

#define TOK   8192
#define DM    128
#define NKEY  500000
#define PDIM  144
#define KSPLIT 128

#define SB     512                 // sim grid (blocks)
#define NPASS  7813                // ceil(500000 / 64)
#define NCAND  (SB * 16)           // 8192 candidates per query

typedef __attribute__((ext_vector_type(8))) short short8;
typedef __attribute__((ext_vector_type(4))) float f32x4;

__device__ __forceinline__ short f2bf(float x) {
    union { float f; unsigned u; } v; v.f = x;
    unsigned r = v.u + 0x7FFFu + ((v.u >> 16) & 1u);
    return (short)(r >> 16);
}

// sorted-descending top-16 insert, all static indices (registers only)
__device__ __forceinline__ void ins16(float v, int id, float* tv, int* tix) {
#pragma unroll
    for (int j = 15; j > 0; j--) {
        bool up = v > tv[j];
        bool sh = v > tv[j - 1];
        float nv = sh ? tv[j - 1] : v;
        int   ni = sh ? tix[j - 1] : id;
        tv[j]  = up ? nv : tv[j];
        tix[j] = up ? ni : tix[j];
    }
    if (v > tv[0]) { tv[0] = v; tix[0] = id; }
}

// merge partner lane's descending-sorted top-16 into mine via bitonic merge.
// Both partners end with the identical merged, descending-sorted list.
__device__ __forceinline__ void merge16(float* tv, int* tix, int mask) {
    float ov[16]; int oi[16];
#pragma unroll
    for (int j = 0; j < 16; j++) {
        ov[j] = __shfl_xor(tv[j], mask);
        oi[j] = __shfl_xor(tix[j], mask);
    }
    // top-16 of union: C[i] = max(A[i], B[15-i]); result is bitonic
#pragma unroll
    for (int j = 0; j < 16; j++) {
        bool a = tv[j] >= ov[15 - j];
        float nv = a ? tv[j] : ov[15 - j];
        int   ni = a ? tix[j] : oi[15 - j];
        tv[j] = nv; tix[j] = ni;
    }
    // sort bitonic sequence back to descending: stages d = 8,4,2,1
#pragma unroll
    for (int d = 8; d >= 1; d >>= 1) {
#pragma unroll
        for (int j = 0; j < 16; j++) {
            if ((j & d) == 0) {
                bool sw = tv[j] < tv[j + d];
                float a0 = sw ? tv[j + d] : tv[j];
                float a1 = sw ? tv[j]     : tv[j + d];
                int   b0 = sw ? tix[j + d] : tix[j];
                int   b1 = sw ? tix[j]     : tix[j + d];
                tv[j] = a0; tv[j + d] = a1; tix[j] = b0; tix[j + d] = b1;
            }
        }
    }
}

// ---------------- both embeds in one kernel
__global__ __launch_bounds__(256) void k_embed2(
    const float* __restrict__ x, const float* __restrict__ w,
    const float* __restrict__ b, const float* __restrict__ wpe,
    float* __restrict__ out, const float* __restrict__ rw,
    const float* __restrict__ rb, float* __restrict__ rout)
{
    int bid = blockIdx.x;
    if (bid < 4096) {
        int idx = bid * 256 + threadIdx.x;
        int t = idx >> 7, d = idx & 127;
        float acc = b[d] + wpe[(t & 63) * DM + d];
        const float* xr = x + t * 6;
#pragma unroll
        for (int i = 0; i < 6; i++) acc = fmaf(xr[i], w[i * DM + d], acc);
        out[idx] = acc;
    } else {
        int idx = (bid - 4096) * 256 + threadIdx.x;
        int t = idx >> 7, d = idx & 127;
        float acc = rb[d];
        const float* xr = x + t * 6;
#pragma unroll
        for (int i = 0; i < 6; i++) acc = fmaf(xr[i], rw[i * DM + d], acc);
        rout[idx] = acc;
    }
}

// ---------------- layernorm (only for lnf now)
__global__ __launch_bounds__(256) void k_ln(
    const float* __restrict__ in, const float* __restrict__ g,
    const float* __restrict__ b, float* __restrict__ out)
{
    int row = blockIdx.x * 4 + (threadIdx.x >> 6);
    int lane = threadIdx.x & 63;
    const float* r = in + row * DM;
    float v0 = r[lane], v1 = r[lane + 64];
    float s = v0 + v1, ss = v0 * v0 + v1 * v1;
#pragma unroll
    for (int o = 32; o; o >>= 1) { s += __shfl_down(s, o); ss += __shfl_down(ss, o); }
    s = __shfl(s, 0); ss = __shfl(ss, 0);
    float mean = s * (1.f / 128.f);
    float var = ss * (1.f / 128.f) - mean * mean;
    float rstd = rsqrtf(var + 1e-5f);
    out[row * DM + lane]      = (v0 - mean) * rstd * g[lane]      + b[lane];
    out[row * DM + lane + 64] = (v1 - mean) * rstd * g[lane + 64] + b[lane + 64];
}

// ---------------- LN-fused GEMM, K=128: C = LN(A) @ W + bias, optional gelu
template<int ACT>
__global__ __launch_bounds__(256) void k_gemmln(
    const float* __restrict__ A, const float* __restrict__ g,
    const float* __restrict__ bln, const float* __restrict__ W,
    const float* __restrict__ bias, float* __restrict__ C, int NC)
{
    __shared__ float As[128][68];   // [k][m] normalized
    __shared__ float Ws[16][68];
    const int tid = threadIdx.x;
    const int m0 = blockIdx.x * 64, n0 = blockIdx.y * 64;
    {
        int row = tid >> 2, part = tid & 3;
        const float* ar = A + (long)(m0 + row) * 128 + part * 32;
        float v[32];
        float s = 0.f, ss = 0.f;
#pragma unroll
        for (int i2 = 0; i2 < 8; i2++) {
            float4 t = *(const float4*)(ar + i2 * 4);
            v[i2 * 4 + 0] = t.x; v[i2 * 4 + 1] = t.y;
            v[i2 * 4 + 2] = t.z; v[i2 * 4 + 3] = t.w;
            s += t.x + t.y + t.z + t.w;
            ss += t.x * t.x + t.y * t.y + t.z * t.z + t.w * t.w;
        }
        s += __shfl_xor(s, 1); s += __shfl_xor(s, 2);
        ss += __shfl_xor(ss, 1); ss += __shfl_xor(ss, 2);
        float mean = s * (1.f / 128.f);
        float rstd = rsqrtf(ss * (1.f / 128.f) - mean * mean + 1e-5f);
#pragma unroll
        for (int i = 0; i < 32; i++) {
            int d = part * 32 + i;
            As[d][row] = (v[i] - mean) * rstd * g[d] + bln[d];
        }
    }
    const int ty = tid >> 4, tx = tid & 15;
    float acc[4][4];
#pragma unroll
    for (int i = 0; i < 4; i++)
#pragma unroll
        for (int j = 0; j < 4; j++) acc[i][j] = 0.f;
    __syncthreads();
    for (int k0 = 0; k0 < 128; k0 += 16) {
        {
            int kk = tid >> 4, n = (tid & 15) * 4;
            *(float4*)&Ws[kk][n] = *(const float4*)(W + (long)(k0 + kk) * NC + n0 + n);
        }
        __syncthreads();
#pragma unroll
        for (int kk = 0; kk < 16; kk++) {
            float av[4], wv[4];
            *(float4*)av = *(const float4*)&As[k0 + kk][ty * 4];
            *(float4*)wv = *(const float4*)&Ws[kk][tx * 4];
#pragma unroll
            for (int i = 0; i < 4; i++)
#pragma unroll
                for (int j = 0; j < 4; j++) acc[i][j] = fmaf(av[i], wv[j], acc[i][j]);
        }
        __syncthreads();
    }
#pragma unroll
    for (int i = 0; i < 4; i++) {
        int m = m0 + ty * 4 + i;
#pragma unroll
        for (int j = 0; j < 4; j++) {
            int n = n0 + tx * 4 + j;
            float u = acc[i][j] + bias[n];
            if (ACT) {
                float z = 0.7978845608028654f * (u + 0.044715f * u * u * u);
                z = fminf(fmaxf(z, -15.f), 15.f);
                float t = __expf(2.f * z);
                u = 0.5f * u * (1.f + (t - 1.f) / (t + 1.f));
            }
            C[(long)m * NC + n] = u;
        }
    }
}

// ---------------- plain GEMM (proj / mlp): C = A @ W + bias (+resid)
template<int KD>
__global__ __launch_bounds__(256) void k_gemm(
    const float* __restrict__ A, const float* __restrict__ W,
    const float* __restrict__ bias, const float* __restrict__ resid,
    float* __restrict__ C, int NC)
{
    __shared__ float As[16][68];
    __shared__ float Ws[16][68];
    const int m0 = blockIdx.x * 64, n0 = blockIdx.y * 64;
    const int tid = threadIdx.x, ty = tid >> 4, tx = tid & 15;
    float acc[4][4];
#pragma unroll
    for (int i = 0; i < 4; i++)
#pragma unroll
        for (int j = 0; j < 4; j++) acc[i][j] = 0.f;
    for (int k0 = 0; k0 < KD; k0 += 16) {
        {
            int m = tid >> 2, kk = (tid & 3) * 4;
            float4 av = *(const float4*)(A + (long)(m0 + m) * KD + k0 + kk);
            As[kk][m] = av.x; As[kk + 1][m] = av.y; As[kk + 2][m] = av.z; As[kk + 3][m] = av.w;
        }
        {
            int kk = tid >> 4, n = (tid & 15) * 4;
            *(float4*)&Ws[kk][n] = *(const float4*)(W + (long)(k0 + kk) * NC + n0 + n);
        }
        __syncthreads();
#pragma unroll
        for (int kk = 0; kk < 16; kk++) {
            float av[4], wv[4];
            *(float4*)av = *(const float4*)&As[kk][ty * 4];
            *(float4*)wv = *(const float4*)&Ws[kk][tx * 4];
#pragma unroll
            for (int i = 0; i < 4; i++)
#pragma unroll
                for (int j = 0; j < 4; j++) acc[i][j] = fmaf(av[i], wv[j], acc[i][j]);
        }
        __syncthreads();
    }
#pragma unroll
    for (int i = 0; i < 4; i++) {
        int m = m0 + ty * 4 + i;
#pragma unroll
        for (int j = 0; j < 4; j++) {
            int n = n0 + tx * 4 + j;
            float u = acc[i][j] + bias[n];
            if (resid) u += resid[(long)m * NC + n];
            C[(long)m * NC + n] = u;
        }
    }
}

// ---------------- attention: one block per (b, h). S=64, hd=32, causal.
__global__ __launch_bounds__(256) void k_attn(
    const float* __restrict__ qkv, float* __restrict__ o)
{
    int b = blockIdx.x >> 2, h = blockIdx.x & 3;
    __shared__ float q[64][33], k[64][33], v[64][33];
    __shared__ float att[64][65];
    int tid = threadIdx.x;
#pragma unroll
    for (int it = 0; it < 8; it++) {
        int idx = it * 256 + tid; int s = idx >> 5, d = idx & 31;
        const float* base = qkv + (long)(b * 64 + s) * 384 + h * 32 + d;
        q[s][d] = base[0]; k[s][d] = base[128]; v[s][d] = base[256];
    }
    __syncthreads();
    {
        int sq = tid >> 2, sk0 = (tid & 3) * 16;
        float e[16]; float mx = -3.0e38f;
#pragma unroll
        for (int j = 0; j < 16; j++) {
            int sk = sk0 + j;
            float a = 0.f;
#pragma unroll
            for (int d = 0; d < 32; d++) a = fmaf(q[sq][d], k[sk][d], a);
            a = (sk <= sq) ? a * 0.17677669529663687f : -3.0e38f;
            e[j] = a; mx = fmaxf(mx, a);
        }
        mx = fmaxf(mx, __shfl_xor(mx, 1)); mx = fmaxf(mx, __shfl_xor(mx, 2));
        float s = 0.f;
#pragma unroll
        for (int j = 0; j < 16; j++) { e[j] = __expf(e[j] - mx); s += e[j]; }
        s += __shfl_xor(s, 1); s += __shfl_xor(s, 2);
        float inv = 1.f / s;
#pragma unroll
        for (int j = 0; j < 16; j++) att[sq][sk0 + j] = e[j] * inv;
    }
    __syncthreads();
#pragma unroll
    for (int it = 0; it < 8; it++) {
        int idx = it * 256 + tid; int s = idx >> 5, d = idx & 31;
        float acc = 0.f;
        for (int sk = 0; sk < 64; sk++) acc = fmaf(att[s][sk], v[sk][d], acc);
        o[(long)(b * 64 + s) * 128 + h * 32 + d] = acc;
    }
}

// ---------------- head GEMM split-K
template<int NC>
__global__ __launch_bounds__(256) void k_head(
    const float* __restrict__ A, const float* __restrict__ W,
    float* __restrict__ part)
{
    constexpr int NPT = NC / 16;
    __shared__ float As[16][132];
    __shared__ float Ws[16][NC + 4];
    const int tid = threadIdx.x, ty = tid >> 4, tx = tid & 15;
    float acc[8][NPT];
#pragma unroll
    for (int i = 0; i < 8; i++)
#pragma unroll
        for (int j = 0; j < NPT; j++) acc[i][j] = 0.f;
    const int kbase = blockIdx.x * 64;
    for (int kc = 0; kc < 4; kc++) {
        int k0 = kbase + kc * 16;
        {
            int m = tid >> 1, kk = (tid & 1) * 8;
            const float* ap = A + (long)m * 8192 + k0 + kk;
            float4 a0 = *(const float4*)ap;
            float4 a1 = *(const float4*)(ap + 4);
            As[kk + 0][m] = a0.x; As[kk + 1][m] = a0.y; As[kk + 2][m] = a0.z; As[kk + 3][m] = a0.w;
            As[kk + 4][m] = a1.x; As[kk + 5][m] = a1.y; As[kk + 6][m] = a1.z; As[kk + 7][m] = a1.w;
        }
        for (int e = tid; e < 16 * NC; e += 256) {
            int kk = e / NC, n = e - kk * NC;
            Ws[kk][n] = W[(long)(k0 + kk) * NC + n];
        }
        __syncthreads();
#pragma unroll
        for (int kk = 0; kk < 16; kk++) {
            float av[8];
            *(float4*)av       = *(const float4*)&As[kk][ty * 8];
            *(float4*)(av + 4) = *(const float4*)&As[kk][ty * 8 + 4];
#pragma unroll
            for (int j = 0; j < NPT; j++) {
                float wv = Ws[kk][tx * NPT + j];
#pragma unroll
                for (int i = 0; i < 8; i++) acc[i][j] = fmaf(av[i], wv, acc[i][j]);
            }
        }
        __syncthreads();
    }
    float* pp = part + (long)blockIdx.x * (128 * NC);
#pragma unroll
    for (int i = 0; i < 8; i++)
#pragma unroll
        for (int j = 0; j < NPT; j++)
            pp[(ty * 8 + i) * NC + tx * NPT + j] = acc[i][j];
}

__global__ __launch_bounds__(256) void k_redhead(
    const float* __restrict__ part, const float* __restrict__ bias,
    float* __restrict__ out, int MN, int NC)
{
    int idx = blockIdx.x * 256 + threadIdx.x;
    if (idx >= MN) return;
    float s = bias[idx % NC];
    for (int b = 0; b < KSPLIT; b++) s += part[(long)b * MN + idx];
    out[idx] = s;
}

// qe reduction + per-row sum of squares (for l2 normalize)
__global__ __launch_bounds__(256) void k_redhead_qe(
    const float* __restrict__ part, const float* __restrict__ bias,
    float* __restrict__ out, float* __restrict__ ssq)
{
    __shared__ float hsum[4];
    int tid = threadIdx.x;
    int idx = blockIdx.x * 256 + tid;
    float s = bias[idx & 127];
    for (int b = 0; b < KSPLIT; b++) s += part[(long)b * 16384 + idx];
    out[idx] = s;
    float sq = s * s;
#pragma unroll
    for (int o = 32; o; o >>= 1) sq += __shfl_down(sq, o);
    if ((tid & 63) == 0) hsum[tid >> 6] = sq;
    __syncthreads();
    if (tid == 0)   ssq[blockIdx.x * 2]     = hsum[0] + hsum[1];
    if (tid == 128) ssq[blockIdx.x * 2 + 1] = hsum[2] + hsum[3];
}

// ---------------- build L2-normalized query B-fragments (bf16, hi only)
__global__ __launch_bounds__(256) void k_qprep(
    const float* __restrict__ qe, const float* __restrict__ ssq,
    short* __restrict__ qfh)
{
    int idx = blockIdx.x * 256 + threadIdx.x;     // 16384
    int j = idx & 7, lane = (idx >> 3) & 63, t = (idx >> 9) & 7, ks = idx >> 12;
    int n = t * 16 + (lane & 15);
    int d = ks * 32 + (lane >> 4) * 8 + j;
    float inv = 1.f / fmaxf(sqrtf(ssq[n]), 1e-12f);
    qfh[idx] = f2bf(qe[n * 128 + d] * inv);
}

__device__ __forceinline__ void cvt8h(float4 a, float4 b, int4& hi) {
    float e[8] = {a.x, a.y, a.z, a.w, b.x, b.y, b.z, b.w};
    int h[8];
#pragma unroll
    for (int i = 0; i < 8; i++) h[i] = (int)f2bf(e[i]) & 0xFFFF;
    hi.x = h[0] | (h[1] << 16); hi.y = h[2] | (h[3] << 16);
    hi.z = h[4] | (h[5] << 16); hi.w = h[6] | (h[7] << 16);
}

// ---------------- sim via single bf16 MFMA (screening), register top-16.
// 8 waves; wave w owns 16 queries. In the MFMA accumulator, lane (quad,l15)
// holds sim[key = m*16 + quad*4 + r][query = w*16 + l15] -> the 4 quads
// partition the 64 keys of a pass, so top-16 is maintained directly from
// the accumulator registers (no sim LDS round-trip). Frags double-buffered
// (2 x 16 KB) -> one barrier per pass. Approximate values are exact-rescored
// in k_merge before final selection.
__global__ __launch_bounds__(512, 4) void k_sim3(
    const float* __restrict__ keys, const short* __restrict__ qfh,
    float* __restrict__ cval, int* __restrict__ cidx)
{
    __shared__ __align__(16) short afh[2][8192];   // 2 x 16 KB frag buffers

    const int tid = threadIdx.x;
    const int w = tid >> 6, lane = tid & 63;
    const int quad = lane >> 4, l15 = lane & 15;

    short8 bh[4];
    {
        const short8* qfh8 = (const short8*)qfh;
#pragma unroll
        for (int ks = 0; ks < 4; ks++) bh[ks] = qfh8[(ks * 8 + w) * 64 + lane];
    }

    float tv[16]; int tix[16];
#pragma unroll
    for (int j = 0; j < 16; j++) { tv[j] = -3.0e38f; tix[j] = 0; }

    // staging role: key r = tid>>3, octet o = tid&7 (d = o*8 and 64+o*8)
    const int r = tid >> 3, o = tid & 7;
    const int mt = r >> 4, rr = r & 15;
    const int L = (o & 3) * 16 + rr;
    const int da = ((mt * 4 + (o >> 2)) * 64 + L) * 8;
    const int db = ((mt * 4 + 2 + (o >> 2)) * 64 + L) * 8;

    float4 R[4];
    int p = blockIdx.x;
    {
        int gk = p * 64 + r;
        const float* kp = keys + (long)gk * 128 + o * 8;
        bool ok = gk < NKEY;
        R[0] = ok ? *(const float4*)kp        : make_float4(0.f,0.f,0.f,0.f);
        R[1] = ok ? *(const float4*)(kp + 4)  : make_float4(0.f,0.f,0.f,0.f);
        R[2] = ok ? *(const float4*)(kp + 64) : make_float4(0.f,0.f,0.f,0.f);
        R[3] = ok ? *(const float4*)(kp + 68) : make_float4(0.f,0.f,0.f,0.f);
    }

    int cur = 0;
    for (; p < NPASS; p += SB) {
        {
            int4 hi;
            cvt8h(R[0], R[1], hi);
            *(int4*)(afh[cur] + da) = hi;
            cvt8h(R[2], R[3], hi);
            *(int4*)(afh[cur] + db) = hi;
        }
        {
            int pn = p + SB;
            if (pn < NPASS) {
                int gk = pn * 64 + r;
                const float* kp = keys + (long)gk * 128 + o * 8;
                bool ok = gk < NKEY;
                R[0] = ok ? *(const float4*)kp        : make_float4(0.f,0.f,0.f,0.f);
                R[1] = ok ? *(const float4*)(kp + 4)  : make_float4(0.f,0.f,0.f,0.f);
                R[2] = ok ? *(const float4*)(kp + 64) : make_float4(0.f,0.f,0.f,0.f);
                R[3] = ok ? *(const float4*)(kp + 68) : make_float4(0.f,0.f,0.f,0.f);
            }
        }
        __syncthreads();    // frags[cur] ready; frags[cur^1] reads all retired

        f32x4 acc[4];
#pragma unroll
        for (int m = 0; m < 4; m++) acc[m] = (f32x4){0.f, 0.f, 0.f, 0.f};
        const short8* ah8 = (const short8*)afh[cur];
#pragma unroll
        for (int ks = 0; ks < 4; ks++) {
            short8 ah[4];
#pragma unroll
            for (int m = 0; m < 4; m++) ah[m] = ah8[(m * 4 + ks) * 64 + lane];
#pragma unroll
            for (int m = 0; m < 4; m++)
                acc[m] = __builtin_amdgcn_mfma_f32_16x16x32_bf16(ah[m], bh[ks], acc[m], 0, 0, 0);
        }

        // top-16 update straight from accumulator registers
        int limit = NKEY - p * 64;
        float thr = tv[15];
#pragma unroll
        for (int m = 0; m < 4; m++) {
            float mx = fmaxf(fmaxf(acc[m][0], acc[m][1]), fmaxf(acc[m][2], acc[m][3]));
            if (mx > thr) {
                int kl = m * 16 + quad * 4;
#pragma unroll
                for (int r4 = 0; r4 < 4; r4++) {
                    float v = acc[m][r4];
                    if (v > thr && (kl + r4) < limit) {
                        ins16(v, p * 64 + kl + r4, tv, tix);
                        thr = tv[15];
                    }
                }
            }
        }
        cur ^= 1;
    }

    // cross-quad merge: after 2 rounds every lane holds the block's top-16
    // for its wave's query l15 (quads partition keys, queries repeat per quad)
    merge16(tv, tix, 16);
    merge16(tv, tix, 32);

    if (quad == 0) {
        int q = w * 16 + l15;
        long ob = ((long)blockIdx.x * 128 + q) * 16;
#pragma unroll
        for (int j = 0; j < 16; j++) { cval[ob + j] = tv[j]; cidx[ob + j] = tix[j]; }
    }
}

// ---------------- merge candidates (approx top-32), exact fp32 rescore,
// exact top-16 + softmax, gather memory_values, fuse
__global__ __launch_bounds__(256) void k_merge(
    const float* __restrict__ cval, const int* __restrict__ cidx,
    const float* __restrict__ base, const float* __restrict__ mvals,
    const float* __restrict__ fw, const float* __restrict__ keys,
    const float* __restrict__ qe, const float* __restrict__ ssq,
    float* __restrict__ out)
{
    __shared__ float sv[NCAND];
    __shared__ int   si[NCAND];
    __shared__ float wv[4]; __shared__ int wi[4];
    __shared__ int   tis[32];
    __shared__ float exv[32];
    __shared__ float fvs[16]; __shared__ int fis[16];
    const int q = blockIdx.x, tid = threadIdx.x;
    for (int i = tid; i < NCAND; i += 256) {
        sv[i] = cval[(i >> 4) * 2048 + q * 16 + (i & 15)];
        si[i] = cidx[(i >> 4) * 2048 + q * 16 + (i & 15)];
    }
    __syncthreads();
    // approx top-32 (screening values; candidate indices are what matters)
    for (int rsel = 0; rsel < 32; rsel++) {
        float bv = -3.0e38f; int bp = -1;
        for (int i = tid; i < NCAND; i += 256) {
            float v = sv[i];
            if (v > bv) { bv = v; bp = i; }
        }
#pragma unroll
        for (int o = 32; o; o >>= 1) {
            float ov = __shfl_down(bv, o); int op = __shfl_down(bp, o);
            if (ov > bv) { bv = ov; bp = op; }
        }
        if ((tid & 63) == 0) { wv[tid >> 6] = bv; wi[tid >> 6] = bp; }
        __syncthreads();
        if (tid == 0) {
            float b2 = wv[0]; int p2 = wi[0];
            for (int ww = 1; ww < 4; ww++) if (wv[ww] > b2) { b2 = wv[ww]; p2 = wi[ww]; }
            tis[rsel] = si[p2]; sv[p2] = -3.0e38f;
        }
        __syncthreads();
    }
    // exact fp32 rescore of the 32 candidates: 8 lanes x 16 dims each
    {
        int c = tid >> 3, pp = tid & 7;
        int idx = tis[c];
        const float* kr = keys + (long)idx * 128 + pp * 16;
        const float* qr = qe + q * 128 + pp * 16;
        float s = 0.f;
#pragma unroll
        for (int d2 = 0; d2 < 16; d2++) s = fmaf(qr[d2], kr[d2], s);
        s += __shfl_xor(s, 1); s += __shfl_xor(s, 2); s += __shfl_xor(s, 4);
        if (pp == 0) exv[c] = s;
    }
    __syncthreads();
    // exact top-16 of the 32 (wave-parallel argmax rounds)
    if (tid < 64) {
        float inv = 1.f / fmaxf(sqrtf(ssq[q]), 1e-12f);
        float v = (tid < 32) ? exv[tid] : -3.0e38f;
        int   id = (tid < 32) ? tis[tid] : -1;
        for (int rsel = 0; rsel < 16; rsel++) {
            float bv = v; int bi = id;
#pragma unroll
            for (int o = 32; o; o >>= 1) {
                float ov = __shfl_xor(bv, o); int oi = __shfl_xor(bi, o);
                if (ov > bv) { bv = ov; bi = oi; }
            }
            if (v == bv && id == bi) v = -3.0e38f;   // deactivate winner
            if (tid == 0) { fvs[rsel] = bv * inv; fis[rsel] = bi; }
        }
    }
    __syncthreads();
    float alpha = 1.f / (1.f + __expf(-fw[0]));
    if (tid < PDIM) {
        float m = fvs[0];                            // descending -> max first
        float wgt[16]; float s = 0.f;
#pragma unroll
        for (int rsel = 0; rsel < 16; rsel++) { wgt[rsel] = __expf(fvs[rsel] - m); s += wgt[rsel]; }
        float inv = 1.f / s;
        float ret = 0.f;
#pragma unroll
        for (int rsel = 0; rsel < 16; rsel++) ret += wgt[rsel] * inv * mvals[(long)fis[rsel] * PDIM + tid];
        out[q * PDIM + tid] = alpha * base[q * PDIM + tid] + (1.f - alpha) * ret;
    }
}

// ---------------- launch
extern "C" void kernel_launch(void* const* d_in, const int* in_sizes, int n_in,
                              void* d_out, int out_size, void* d_ws, size_t ws_size,
                              hipStream_t stream)
{
    const float* x      = (const float*)d_in[0];
    const float* keys   = (const float*)d_in[1];
    const float* mvals  = (const float*)d_in[2];
    const float* wpe    = (const float*)d_in[3];
    const float* w_in   = (const float*)d_in[4];
    const float* b_in   = (const float*)d_in[5];
    const float* ln1_g  = (const float*)d_in[6];
    const float* ln1_b  = (const float*)d_in[7];
    const float* attn_w = (const float*)d_in[8];
    const float* attn_b = (const float*)d_in[9];
    const float* attn_pw= (const float*)d_in[10];
    const float* attn_pb= (const float*)d_in[11];
    const float* ln2_g  = (const float*)d_in[12];
    const float* ln2_b  = (const float*)d_in[13];
    const float* fc_w   = (const float*)d_in[14];
    const float* fc_b   = (const float*)d_in[15];
    const float* mlp_pw = (const float*)d_in[16];
    const float* mlp_pb = (const float*)d_in[17];
    const float* lnf_g  = (const float*)d_in[18];
    const float* lnf_b  = (const float*)d_in[19];
    const float* w_out  = (const float*)d_in[20];
    const float* b_out  = (const float*)d_in[21];
    const float* ret_w1 = (const float*)d_in[22];
    const float* ret_b1 = (const float*)d_in[23];
    const float* ret_w2 = (const float*)d_in[24];
    const float* ret_b2 = (const float*)d_in[25];
    const float* fw     = (const float*)d_in[26];
    float* out = (float*)d_out;

    float* ws   = (float*)d_ws;
    float* h    = ws + 0;            // 1048576
    float* bufA = ws + 1048576;      // 1048576 (attn out / lnf out)
    float* bufB = ws + 2097152;      // 4194304 (qkv / fc act)
    float* bufO = ws + 6291456;      // 1048576 (retrieval embed)
    float* part = ws + 7340032;      // 2359296
    float* base = ws + 9699328;      // 18432
    float* qe   = ws + 9717760;      // 16384
    float* ssq  = ws + 9734144;      // 128
    short* qfh  = (short*)(ws + 9734272);   // 16384 shorts
    float* cval = bufB;                     // alias: bufB dead after backbone
    int*   cidx = (int*)part;               // alias: part dead after redheads

    k_embed2<<<8192, 256, 0, stream>>>(x, w_in, b_in, wpe, h, ret_w1, ret_b1, bufO);
    for (int l = 0; l < 3; l++) {
        k_gemmln<0><<<dim3(128, 6), 256, 0, stream>>>(h, ln1_g + l * 128,
            ln1_b + l * 128, attn_w + l * 49152, attn_b + l * 384, bufB, 384);
        k_attn<<<512, 256, 0, stream>>>(bufB, bufA);
        k_gemm<128><<<dim3(128, 2), 256, 0, stream>>>(bufA, attn_pw + l * 16384,
            attn_pb + l * 128, h, h, 128);
        k_gemmln<1><<<dim3(128, 8), 256, 0, stream>>>(h, ln2_g + l * 128,
            ln2_b + l * 128, fc_w + l * 65536, fc_b + l * 512, bufB, 512);
        k_gemm<512><<<dim3(128, 2), 256, 0, stream>>>(bufB, mlp_pw + l * 65536,
            mlp_pb + l * 128, h, h, 128);
    }
    k_ln<<<2048, 256, 0, stream>>>(h, lnf_g, lnf_b, bufA);
    k_head<144><<<KSPLIT, 256, 0, stream>>>(bufA, w_out, part);
    k_redhead<<<72, 256, 0, stream>>>(part, b_out, base, 128 * 144, 144);

    k_head<128><<<KSPLIT, 256, 0, stream>>>(bufO, ret_w2, part);
    k_redhead_qe<<<64, 256, 0, stream>>>(part, ret_b2, qe, ssq);
    k_qprep<<<64, 256, 0, stream>>>(qe, ssq, qfh);

    k_sim3<<<SB, 512, 0, stream>>>(keys, qfh, cval, cidx);
    k_merge<<<128, 256, 0, stream>>>(cval, cidx, base, mvals, fw, keys, qe, ssq, out);
}

// Round 2
// 1052.248 us; speedup vs baseline: 1.1775x; 1.1775x over previous
//
#include <hip/hip_runtime.h>
#include <math.h>

#define TOK   8192
#define DM    128
#define NKEY  500000
#define PDIM  144
#define KSPLIT 128

#define SB     512                 // sim grid (blocks)
#define NPASS  7813                // ceil(500000 / 64)
#define NCAND  (SB * 16)           // 8192 candidates per query

typedef __attribute__((ext_vector_type(8))) short short8;
typedef __attribute__((ext_vector_type(4))) float f32x4;

__device__ __forceinline__ short f2bf(float x) {
    union { float f; unsigned u; } v; v.f = x;
    unsigned r = v.u + 0x7FFFu + ((v.u >> 16) & 1u);
    return (short)(r >> 16);
}

// hw packed f32->bf16 (RNE), 1 instruction for 2 elements
__device__ __forceinline__ int cvtpk(float a, float b) {
    int r;
    asm("v_cvt_pk_bf16_f32 %0, %1, %2" : "=v"(r) : "v"(a), "v"(b));
    return r;
}

// sorted-descending top-4 insert, registers only (~21 VALU)
__device__ __forceinline__ void ins4(float v, int id, float* tv, int* tix) {
#pragma unroll
    for (int j = 3; j > 0; j--) {
        bool up = v > tv[j];
        bool sh = v > tv[j - 1];
        float nv = sh ? tv[j - 1] : v;
        int   ni = sh ? tix[j - 1] : id;
        tv[j]  = up ? nv : tv[j];
        tix[j] = up ? ni : tix[j];
    }
    if (v > tv[0]) { tv[0] = v; tix[0] = id; }
}

// ---------------- both embeds in one kernel
__global__ __launch_bounds__(256) void k_embed2(
    const float* __restrict__ x, const float* __restrict__ w,
    const float* __restrict__ b, const float* __restrict__ wpe,
    float* __restrict__ out, const float* __restrict__ rw,
    const float* __restrict__ rb, float* __restrict__ rout)
{
    int bid = blockIdx.x;
    if (bid < 4096) {
        int idx = bid * 256 + threadIdx.x;
        int t = idx >> 7, d = idx & 127;
        float acc = b[d] + wpe[(t & 63) * DM + d];
        const float* xr = x + t * 6;
#pragma unroll
        for (int i = 0; i < 6; i++) acc = fmaf(xr[i], w[i * DM + d], acc);
        out[idx] = acc;
    } else {
        int idx = (bid - 4096) * 256 + threadIdx.x;
        int t = idx >> 7, d = idx & 127;
        float acc = rb[d];
        const float* xr = x + t * 6;
#pragma unroll
        for (int i = 0; i < 6; i++) acc = fmaf(xr[i], rw[i * DM + d], acc);
        rout[idx] = acc;
    }
}

// ---------------- layernorm (only for lnf now)
__global__ __launch_bounds__(256) void k_ln(
    const float* __restrict__ in, const float* __restrict__ g,
    const float* __restrict__ b, float* __restrict__ out)
{
    int row = blockIdx.x * 4 + (threadIdx.x >> 6);
    int lane = threadIdx.x & 63;
    const float* r = in + row * DM;
    float v0 = r[lane], v1 = r[lane + 64];
    float s = v0 + v1, ss = v0 * v0 + v1 * v1;
#pragma unroll
    for (int o = 32; o; o >>= 1) { s += __shfl_down(s, o); ss += __shfl_down(ss, o); }
    s = __shfl(s, 0); ss = __shfl(ss, 0);
    float mean = s * (1.f / 128.f);
    float var = ss * (1.f / 128.f) - mean * mean;
    float rstd = rsqrtf(var + 1e-5f);
    out[row * DM + lane]      = (v0 - mean) * rstd * g[lane]      + b[lane];
    out[row * DM + lane + 64] = (v1 - mean) * rstd * g[lane + 64] + b[lane + 64];
}

// ---------------- LN-fused GEMM, K=128: C = LN(A) @ W + bias, optional gelu
template<int ACT>
__global__ __launch_bounds__(256) void k_gemmln(
    const float* __restrict__ A, const float* __restrict__ g,
    const float* __restrict__ bln, const float* __restrict__ W,
    const float* __restrict__ bias, float* __restrict__ C, int NC)
{
    __shared__ float As[128][68];   // [k][m] normalized
    __shared__ float Ws[16][68];
    const int tid = threadIdx.x;
    const int m0 = blockIdx.x * 64, n0 = blockIdx.y * 64;
    {
        int row = tid >> 2, part = tid & 3;
        const float* ar = A + (long)(m0 + row) * 128 + part * 32;
        float v[32];
        float s = 0.f, ss = 0.f;
#pragma unroll
        for (int i2 = 0; i2 < 8; i2++) {
            float4 t = *(const float4*)(ar + i2 * 4);
            v[i2 * 4 + 0] = t.x; v[i2 * 4 + 1] = t.y;
            v[i2 * 4 + 2] = t.z; v[i2 * 4 + 3] = t.w;
            s += t.x + t.y + t.z + t.w;
            ss += t.x * t.x + t.y * t.y + t.z * t.z + t.w * t.w;
        }
        s += __shfl_xor(s, 1); s += __shfl_xor(s, 2);
        ss += __shfl_xor(ss, 1); ss += __shfl_xor(ss, 2);
        float mean = s * (1.f / 128.f);
        float rstd = rsqrtf(ss * (1.f / 128.f) - mean * mean + 1e-5f);
#pragma unroll
        for (int i = 0; i < 32; i++) {
            int d = part * 32 + i;
            As[d][row] = (v[i] - mean) * rstd * g[d] + bln[d];
        }
    }
    const int ty = tid >> 4, tx = tid & 15;
    float acc[4][4];
#pragma unroll
    for (int i = 0; i < 4; i++)
#pragma unroll
        for (int j = 0; j < 4; j++) acc[i][j] = 0.f;
    __syncthreads();
    for (int k0 = 0; k0 < 128; k0 += 16) {
        {
            int kk = tid >> 4, n = (tid & 15) * 4;
            *(float4*)&Ws[kk][n] = *(const float4*)(W + (long)(k0 + kk) * NC + n0 + n);
        }
        __syncthreads();
#pragma unroll
        for (int kk = 0; kk < 16; kk++) {
            float av[4], wv[4];
            *(float4*)av = *(const float4*)&As[k0 + kk][ty * 4];
            *(float4*)wv = *(const float4*)&Ws[kk][tx * 4];
#pragma unroll
            for (int i = 0; i < 4; i++)
#pragma unroll
                for (int j = 0; j < 4; j++) acc[i][j] = fmaf(av[i], wv[j], acc[i][j]);
        }
        __syncthreads();
    }
#pragma unroll
    for (int i = 0; i < 4; i++) {
        int m = m0 + ty * 4 + i;
#pragma unroll
        for (int j = 0; j < 4; j++) {
            int n = n0 + tx * 4 + j;
            float u = acc[i][j] + bias[n];
            if (ACT) {
                float z = 0.7978845608028654f * (u + 0.044715f * u * u * u);
                z = fminf(fmaxf(z, -15.f), 15.f);
                float t = __expf(2.f * z);
                u = 0.5f * u * (1.f + (t - 1.f) / (t + 1.f));
            }
            C[(long)m * NC + n] = u;
        }
    }
}

// ---------------- plain GEMM (proj / mlp): C = A @ W + bias (+resid)
template<int KD>
__global__ __launch_bounds__(256) void k_gemm(
    const float* __restrict__ A, const float* __restrict__ W,
    const float* __restrict__ bias, const float* __restrict__ resid,
    float* __restrict__ C, int NC)
{
    __shared__ float As[16][68];
    __shared__ float Ws[16][68];
    const int m0 = blockIdx.x * 64, n0 = blockIdx.y * 64;
    const int tid = threadIdx.x, ty = tid >> 4, tx = tid & 15;
    float acc[4][4];
#pragma unroll
    for (int i = 0; i < 4; i++)
#pragma unroll
        for (int j = 0; j < 4; j++) acc[i][j] = 0.f;
    for (int k0 = 0; k0 < KD; k0 += 16) {
        {
            int m = tid >> 2, kk = (tid & 3) * 4;
            float4 av = *(const float4*)(A + (long)(m0 + m) * KD + k0 + kk);
            As[kk][m] = av.x; As[kk + 1][m] = av.y; As[kk + 2][m] = av.z; As[kk + 3][m] = av.w;
        }
        {
            int kk = tid >> 4, n = (tid & 15) * 4;
            *(float4*)&Ws[kk][n] = *(const float4*)(W + (long)(k0 + kk) * NC + n0 + n);
        }
        __syncthreads();
#pragma unroll
        for (int kk = 0; kk < 16; kk++) {
            float av[4], wv[4];
            *(float4*)av = *(const float4*)&As[kk][ty * 4];
            *(float4*)wv = *(const float4*)&Ws[kk][tx * 4];
#pragma unroll
            for (int i = 0; i < 4; i++)
#pragma unroll
                for (int j = 0; j < 4; j++) acc[i][j] = fmaf(av[i], wv[j], acc[i][j]);
        }
        __syncthreads();
    }
#pragma unroll
    for (int i = 0; i < 4; i++) {
        int m = m0 + ty * 4 + i;
#pragma unroll
        for (int j = 0; j < 4; j++) {
            int n = n0 + tx * 4 + j;
            float u = acc[i][j] + bias[n];
            if (resid) u += resid[(long)m * NC + n];
            C[(long)m * NC + n] = u;
        }
    }
}

// ---------------- attention: one block per (b, h). S=64, hd=32, causal.
__global__ __launch_bounds__(256) void k_attn(
    const float* __restrict__ qkv, float* __restrict__ o)
{
    int b = blockIdx.x >> 2, h = blockIdx.x & 3;
    __shared__ float q[64][33], k[64][33], v[64][33];
    __shared__ float att[64][65];
    int tid = threadIdx.x;
#pragma unroll
    for (int it = 0; it < 8; it++) {
        int idx = it * 256 + tid; int s = idx >> 5, d = idx & 31;
        const float* base = qkv + (long)(b * 64 + s) * 384 + h * 32 + d;
        q[s][d] = base[0]; k[s][d] = base[128]; v[s][d] = base[256];
    }
    __syncthreads();
    {
        int sq = tid >> 2, sk0 = (tid & 3) * 16;
        float e[16]; float mx = -3.0e38f;
#pragma unroll
        for (int j = 0; j < 16; j++) {
            int sk = sk0 + j;
            float a = 0.f;
#pragma unroll
            for (int d = 0; d < 32; d++) a = fmaf(q[sq][d], k[sk][d], a);
            a = (sk <= sq) ? a * 0.17677669529663687f : -3.0e38f;
            e[j] = a; mx = fmaxf(mx, a);
        }
        mx = fmaxf(mx, __shfl_xor(mx, 1)); mx = fmaxf(mx, __shfl_xor(mx, 2));
        float s = 0.f;
#pragma unroll
        for (int j = 0; j < 16; j++) { e[j] = __expf(e[j] - mx); s += e[j]; }
        s += __shfl_xor(s, 1); s += __shfl_xor(s, 2);
        float inv = 1.f / s;
#pragma unroll
        for (int j = 0; j < 16; j++) att[sq][sk0 + j] = e[j] * inv;
    }
    __syncthreads();
#pragma unroll
    for (int it = 0; it < 8; it++) {
        int idx = it * 256 + tid; int s = idx >> 5, d = idx & 31;
        float acc = 0.f;
        for (int sk = 0; sk < 64; sk++) acc = fmaf(att[s][sk], v[sk][d], acc);
        o[(long)(b * 64 + s) * 128 + h * 32 + d] = acc;
    }
}

// ---------------- head GEMM split-K
template<int NC>
__global__ __launch_bounds__(256) void k_head(
    const float* __restrict__ A, const float* __restrict__ W,
    float* __restrict__ part)
{
    constexpr int NPT = NC / 16;
    __shared__ float As[16][132];
    __shared__ float Ws[16][NC + 4];
    const int tid = threadIdx.x, ty = tid >> 4, tx = tid & 15;
    float acc[8][NPT];
#pragma unroll
    for (int i = 0; i < 8; i++)
#pragma unroll
        for (int j = 0; j < NPT; j++) acc[i][j] = 0.f;
    const int kbase = blockIdx.x * 64;
    for (int kc = 0; kc < 4; kc++) {
        int k0 = kbase + kc * 16;
        {
            int m = tid >> 1, kk = (tid & 1) * 8;
            const float* ap = A + (long)m * 8192 + k0 + kk;
            float4 a0 = *(const float4*)ap;
            float4 a1 = *(const float4*)(ap + 4);
            As[kk + 0][m] = a0.x; As[kk + 1][m] = a0.y; As[kk + 2][m] = a0.z; As[kk + 3][m] = a0.w;
            As[kk + 4][m] = a1.x; As[kk + 5][m] = a1.y; As[kk + 6][m] = a1.z; As[kk + 7][m] = a1.w;
        }
        for (int e = tid; e < 16 * NC; e += 256) {
            int kk = e / NC, n = e - kk * NC;
            Ws[kk][n] = W[(long)(k0 + kk) * NC + n];
        }
        __syncthreads();
#pragma unroll
        for (int kk = 0; kk < 16; kk++) {
            float av[8];
            *(float4*)av       = *(const float4*)&As[kk][ty * 8];
            *(float4*)(av + 4) = *(const float4*)&As[kk][ty * 8 + 4];
#pragma unroll
            for (int j = 0; j < NPT; j++) {
                float wv = Ws[kk][tx * NPT + j];
#pragma unroll
                for (int i = 0; i < 8; i++) acc[i][j] = fmaf(av[i], wv, acc[i][j]);
            }
        }
        __syncthreads();
    }
    float* pp = part + (long)blockIdx.x * (128 * NC);
#pragma unroll
    for (int i = 0; i < 8; i++)
#pragma unroll
        for (int j = 0; j < NPT; j++)
            pp[(ty * 8 + i) * NC + tx * NPT + j] = acc[i][j];
}

__global__ __launch_bounds__(256) void k_redhead(
    const float* __restrict__ part, const float* __restrict__ bias,
    float* __restrict__ out, int MN, int NC)
{
    int idx = blockIdx.x * 256 + threadIdx.x;
    if (idx >= MN) return;
    float s = bias[idx % NC];
    for (int b = 0; b < KSPLIT; b++) s += part[(long)b * MN + idx];
    out[idx] = s;
}

// qe reduction + per-row sum of squares (for l2 normalize)
__global__ __launch_bounds__(256) void k_redhead_qe(
    const float* __restrict__ part, const float* __restrict__ bias,
    float* __restrict__ out, float* __restrict__ ssq)
{
    __shared__ float hsum[4];
    int tid = threadIdx.x;
    int idx = blockIdx.x * 256 + tid;
    float s = bias[idx & 127];
    for (int b = 0; b < KSPLIT; b++) s += part[(long)b * 16384 + idx];
    out[idx] = s;
    float sq = s * s;
#pragma unroll
    for (int o = 32; o; o >>= 1) sq += __shfl_down(sq, o);
    if ((tid & 63) == 0) hsum[tid >> 6] = sq;
    __syncthreads();
    if (tid == 0)   ssq[blockIdx.x * 2]     = hsum[0] + hsum[1];
    if (tid == 128) ssq[blockIdx.x * 2 + 1] = hsum[2] + hsum[3];
}

// ---------------- build L2-normalized query B-fragments (bf16, hi only)
__global__ __launch_bounds__(256) void k_qprep(
    const float* __restrict__ qe, const float* __restrict__ ssq,
    short* __restrict__ qfh)
{
    int idx = blockIdx.x * 256 + threadIdx.x;     // 16384
    int j = idx & 7, lane = (idx >> 3) & 63, t = (idx >> 9) & 7, ks = idx >> 12;
    int n = t * 16 + (lane & 15);
    int d = ks * 32 + (lane >> 4) * 8 + j;
    float inv = 1.f / fmaxf(sqrtf(ssq[n]), 1e-12f);
    qfh[idx] = f2bf(qe[n * 128 + d] * inv);
}

// ---------------- sim via single bf16 MFMA (screening), register top-4.
// 8 waves; wave w owns 16 queries. In the MFMA accumulator, lane (quad,l15)
// holds sim[key = m*16 + quad*4 + r][query = w*16 + l15] -> the 4 quads
// partition the 64 keys of a pass. Per pass the lane takes the exact top-2
// of its 16 sims (branchless running scan) and pushes both into a register
// top-4; 4 quads x 4 = 16 candidates/query/block, exact-rescored in k_merge.
// Staging roles are lane-linear in LDS (conflict-free ds_write_b128):
// thread tid writes LDS int4-slots {tid, tid+512}; slot s holds frag
// (t8 = s>>6 = m*4+ks, L = s&63) = key[(s>>8)*16 + (s&15)],
// dims ((s>>4)&15)*8 .. +7.
__global__ __launch_bounds__(512, 4) void k_sim3(
    const float* __restrict__ keys, const short* __restrict__ qfh,
    float* __restrict__ cval, int* __restrict__ cidx)
{
    __shared__ __align__(16) short afh[2][8192];   // 2 x 16 KB frag buffers

    const int tid = threadIdx.x;
    const int w = tid >> 6, lane = tid & 63;
    const int quad = lane >> 4, l15 = lane & 15;

    short8 bh[4];
    {
        const short8* qfh8 = (const short8*)qfh;
#pragma unroll
        for (int ks = 0; ks < 4; ks++) bh[ks] = qfh8[(ks * 8 + w) * 64 + lane];
    }

    float tv[4]; int tix[4];
#pragma unroll
    for (int j = 0; j < 4; j++) { tv[j] = -3.0e38f; tix[j] = 0; }

    // staging role: keys k1 = (tid>>8)*16 + (tid&15), k2 = k1+32;
    // dims dbase..dbase+7 of each
    const int krow = ((tid >> 8) << 4) + (tid & 15);
    const int dbase = ((tid >> 4) & 15) * 8;

    float4 R[4];
    int p = blockIdx.x;
    {
        int gk1 = p * 64 + krow, gk2 = gk1 + 32;
        const float* kp1 = keys + (long)gk1 * 128 + dbase;
        const float* kp2 = keys + (long)gk2 * 128 + dbase;
        bool ok1 = gk1 < NKEY, ok2 = gk2 < NKEY;
        R[0] = ok1 ? *(const float4*)kp1       : make_float4(0.f,0.f,0.f,0.f);
        R[1] = ok1 ? *(const float4*)(kp1 + 4) : make_float4(0.f,0.f,0.f,0.f);
        R[2] = ok2 ? *(const float4*)kp2       : make_float4(0.f,0.f,0.f,0.f);
        R[3] = ok2 ? *(const float4*)(kp2 + 4) : make_float4(0.f,0.f,0.f,0.f);
    }

    int cur = 0;
    for (; p < NPASS; p += SB) {
        {
            int4 h1, h2;
            h1.x = cvtpk(R[0].x, R[0].y); h1.y = cvtpk(R[0].z, R[0].w);
            h1.z = cvtpk(R[1].x, R[1].y); h1.w = cvtpk(R[1].z, R[1].w);
            h2.x = cvtpk(R[2].x, R[2].y); h2.y = cvtpk(R[2].z, R[2].w);
            h2.z = cvtpk(R[3].x, R[3].y); h2.w = cvtpk(R[3].z, R[3].w);
            *(int4*)(afh[cur] + tid * 8)        = h1;   // slot tid
            *(int4*)(afh[cur] + 4096 + tid * 8) = h2;   // slot tid+512
        }
        {
            int pn = p + SB;
            if (pn < NPASS) {
                int gk1 = pn * 64 + krow, gk2 = gk1 + 32;
                const float* kp1 = keys + (long)gk1 * 128 + dbase;
                const float* kp2 = keys + (long)gk2 * 128 + dbase;
                bool ok1 = gk1 < NKEY, ok2 = gk2 < NKEY;
                R[0] = ok1 ? *(const float4*)kp1       : make_float4(0.f,0.f,0.f,0.f);
                R[1] = ok1 ? *(const float4*)(kp1 + 4) : make_float4(0.f,0.f,0.f,0.f);
                R[2] = ok2 ? *(const float4*)kp2       : make_float4(0.f,0.f,0.f,0.f);
                R[3] = ok2 ? *(const float4*)(kp2 + 4) : make_float4(0.f,0.f,0.f,0.f);
            }
        }
        __syncthreads();    // frags[cur] ready; frags[cur^1] reads all retired

        f32x4 acc[4];
#pragma unroll
        for (int m = 0; m < 4; m++) acc[m] = (f32x4){0.f, 0.f, 0.f, 0.f};
        const short8* ah8 = (const short8*)afh[cur];
#pragma unroll
        for (int ks = 0; ks < 4; ks++) {
            short8 ah[4];
#pragma unroll
            for (int m = 0; m < 4; m++) ah[m] = ah8[(m * 4 + ks) * 64 + lane];
#pragma unroll
            for (int m = 0; m < 4; m++)
                acc[m] = __builtin_amdgcn_mfma_f32_16x16x32_bf16(ah[m], bh[ks], acc[m], 0, 0, 0);
        }

        // branchless exact top-2 of the 16 sims (ids are inline consts),
        // then two unconditional register ins4. Padded keys (last pass)
        // have sim exactly 0.0 and can never enter a real top-4.
        {
            float m1 = -3.0e38f, m2 = -3.0e38f;
            int l1 = 0, l2 = 0;
#pragma unroll
            for (int m = 0; m < 4; m++) {
#pragma unroll
                for (int r4 = 0; r4 < 4; r4++) {
                    float v = acc[m][r4];
                    const int lc = m * 16 + r4;
                    bool g1 = v > m1;
                    bool g2 = v > m2;
                    m2 = g1 ? m1 : (g2 ? v : m2);
                    l2 = g1 ? l1 : (g2 ? lc : l2);
                    m1 = g1 ? v : m1;
                    l1 = g1 ? lc : l1;
                }
            }
            int base = p * 64 + quad * 4;
            ins4(m1, base + l1, tv, tix);
            ins4(m2, base + l2, tv, tix);
        }
        cur ^= 1;
    }

    // direct store: 4 quads x top-4 = 16 candidates per (block, query)
    {
        int q = w * 16 + l15;
        long ob = ((long)blockIdx.x * 128 + q) * 16 + quad * 4;
#pragma unroll
        for (int j = 0; j < 4; j++) { cval[ob + j] = tv[j]; cidx[ob + j] = tix[j]; }
    }
}

// ---------------- merge candidates (approx top-32), exact fp32 rescore,
// exact top-16 + softmax, gather memory_values, fuse
__global__ __launch_bounds__(256) void k_merge(
    const float* __restrict__ cval, const int* __restrict__ cidx,
    const float* __restrict__ base, const float* __restrict__ mvals,
    const float* __restrict__ fw, const float* __restrict__ keys,
    const float* __restrict__ qe, const float* __restrict__ ssq,
    float* __restrict__ out)
{
    __shared__ float sv[NCAND];
    __shared__ int   si[NCAND];
    __shared__ float wv[4]; __shared__ int wi[4];
    __shared__ int   tis[32];
    __shared__ float exv[32];
    __shared__ float fvs[16]; __shared__ int fis[16];
    const int q = blockIdx.x, tid = threadIdx.x;
    for (int i = tid; i < NCAND; i += 256) {
        sv[i] = cval[(i >> 4) * 2048 + q * 16 + (i & 15)];
        si[i] = cidx[(i >> 4) * 2048 + q * 16 + (i & 15)];
    }
    __syncthreads();
    // approx top-32 (screening values; candidate indices are what matters)
    for (int rsel = 0; rsel < 32; rsel++) {
        float bv = -3.0e38f; int bp = -1;
        for (int i = tid; i < NCAND; i += 256) {
            float v = sv[i];
            if (v > bv) { bv = v; bp = i; }
        }
#pragma unroll
        for (int o = 32; o; o >>= 1) {
            float ov = __shfl_down(bv, o); int op = __shfl_down(bp, o);
            if (ov > bv) { bv = ov; bp = op; }
        }
        if ((tid & 63) == 0) { wv[tid >> 6] = bv; wi[tid >> 6] = bp; }
        __syncthreads();
        if (tid == 0) {
            float b2 = wv[0]; int p2 = wi[0];
            for (int ww = 1; ww < 4; ww++) if (wv[ww] > b2) { b2 = wv[ww]; p2 = wi[ww]; }
            tis[rsel] = si[p2]; sv[p2] = -3.0e38f;
        }
        __syncthreads();
    }
    // exact fp32 rescore of the 32 candidates: 8 lanes x 16 dims each
    {
        int c = tid >> 3, pp = tid & 7;
        int idx = tis[c];
        const float* kr = keys + (long)idx * 128 + pp * 16;
        const float* qr = qe + q * 128 + pp * 16;
        float s = 0.f;
#pragma unroll
        for (int d2 = 0; d2 < 16; d2++) s = fmaf(qr[d2], kr[d2], s);
        s += __shfl_xor(s, 1); s += __shfl_xor(s, 2); s += __shfl_xor(s, 4);
        if (pp == 0) exv[c] = s;
    }
    __syncthreads();
    // exact top-16 of the 32 (wave-parallel argmax rounds)
    if (tid < 64) {
        float inv = 1.f / fmaxf(sqrtf(ssq[q]), 1e-12f);
        float v = (tid < 32) ? exv[tid] : -3.0e38f;
        int   id = (tid < 32) ? tis[tid] : -1;
        for (int rsel = 0; rsel < 16; rsel++) {
            float bv = v; int bi = id;
#pragma unroll
            for (int o = 32; o; o >>= 1) {
                float ov = __shfl_xor(bv, o); int oi = __shfl_xor(bi, o);
                if (ov > bv) { bv = ov; bi = oi; }
            }
            if (v == bv && id == bi) v = -3.0e38f;   // deactivate winner
            if (tid == 0) { fvs[rsel] = bv * inv; fis[rsel] = bi; }
        }
    }
    __syncthreads();
    float alpha = 1.f / (1.f + __expf(-fw[0]));
    if (tid < PDIM) {
        float m = fvs[0];                            // descending -> max first
        float wgt[16]; float s = 0.f;
#pragma unroll
        for (int rsel = 0; rsel < 16; rsel++) { wgt[rsel] = __expf(fvs[rsel] - m); s += wgt[rsel]; }
        float inv = 1.f / s;
        float ret = 0.f;
#pragma unroll
        for (int rsel = 0; rsel < 16; rsel++) ret += wgt[rsel] * inv * mvals[(long)fis[rsel] * PDIM + tid];
        out[q * PDIM + tid] = alpha * base[q * PDIM + tid] + (1.f - alpha) * ret;
    }
}

// ---------------- launch
extern "C" void kernel_launch(void* const* d_in, const int* in_sizes, int n_in,
                              void* d_out, int out_size, void* d_ws, size_t ws_size,
                              hipStream_t stream)
{
    const float* x      = (const float*)d_in[0];
    const float* keys   = (const float*)d_in[1];
    const float* mvals  = (const float*)d_in[2];
    const float* wpe    = (const float*)d_in[3];
    const float* w_in   = (const float*)d_in[4];
    const float* b_in   = (const float*)d_in[5];
    const float* ln1_g  = (const float*)d_in[6];
    const float* ln1_b  = (const float*)d_in[7];
    const float* attn_w = (const float*)d_in[8];
    const float* attn_b = (const float*)d_in[9];
    const float* attn_pw= (const float*)d_in[10];
    const float* attn_pb= (const float*)d_in[11];
    const float* ln2_g  = (const float*)d_in[12];
    const float* ln2_b  = (const float*)d_in[13];
    const float* fc_w   = (const float*)d_in[14];
    const float* fc_b   = (const float*)d_in[15];
    const float* mlp_pw = (const float*)d_in[16];
    const float* mlp_pb = (const float*)d_in[17];
    const float* lnf_g  = (const float*)d_in[18];
    const float* lnf_b  = (const float*)d_in[19];
    const float* w_out  = (const float*)d_in[20];
    const float* b_out  = (const float*)d_in[21];
    const float* ret_w1 = (const float*)d_in[22];
    const float* ret_b1 = (const float*)d_in[23];
    const float* ret_w2 = (const float*)d_in[24];
    const float* ret_b2 = (const float*)d_in[25];
    const float* fw     = (const float*)d_in[26];
    float* out = (float*)d_out;

    float* ws   = (float*)d_ws;
    float* h    = ws + 0;            // 1048576
    float* bufA = ws + 1048576;      // 1048576 (attn out / lnf out)
    float* bufB = ws + 2097152;      // 4194304 (qkv / fc act)
    float* bufO = ws + 6291456;      // 1048576 (retrieval embed)
    float* part = ws + 7340032;      // 2359296
    float* base = ws + 9699328;      // 18432
    float* qe   = ws + 9717760;      // 16384
    float* ssq  = ws + 9734144;      // 128
    short* qfh  = (short*)(ws + 9734272);   // 16384 shorts
    float* cval = bufB;                     // alias: bufB dead after backbone
    int*   cidx = (int*)part;               // alias: part dead after redheads

    k_embed2<<<8192, 256, 0, stream>>>(x, w_in, b_in, wpe, h, ret_w1, ret_b1, bufO);
    for (int l = 0; l < 3; l++) {
        k_gemmln<0><<<dim3(128, 6), 256, 0, stream>>>(h, ln1_g + l * 128,
            ln1_b + l * 128, attn_w + l * 49152, attn_b + l * 384, bufB, 384);
        k_attn<<<512, 256, 0, stream>>>(bufB, bufA);
        k_gemm<128><<<dim3(128, 2), 256, 0, stream>>>(bufA, attn_pw + l * 16384,
            attn_pb + l * 128, h, h, 128);
        k_gemmln<1><<<dim3(128, 8), 256, 0, stream>>>(h, ln2_g + l * 128,
            ln2_b + l * 128, fc_w + l * 65536, fc_b + l * 512, bufB, 512);
        k_gemm<512><<<dim3(128, 2), 256, 0, stream>>>(bufB, mlp_pw + l * 65536,
            mlp_pb + l * 128, h, h, 128);
    }
    k_ln<<<2048, 256, 0, stream>>>(h, lnf_g, lnf_b, bufA);
    k_head<144><<<KSPLIT, 256, 0, stream>>>(bufA, w_out, part);
    k_redhead<<<72, 256, 0, stream>>>(part, b_out, base, 128 * 144, 144);

    k_head<128><<<KSPLIT, 256, 0, stream>>>(bufO, ret_w2, part);
    k_redhead_qe<<<64, 256, 0, stream>>>(part, ret_b2, qe, ssq);
    k_qprep<<<64, 256, 0, stream>>>(qe, ssq, qfh);

    k_sim3<<<SB, 512, 0, stream>>>(keys, qfh, cval, cidx);
    k_merge<<<128, 256, 0, stream>>>(cval, cidx, base, mvals, fw, keys, qe, ssq, out);
}